// Round 1
// baseline (764.492 us; speedup 1.0000x reference)
//
#include <hip/hip_runtime.h>
#include <hip/hip_bf16.h>
#include <math.h>

#define NN   8192
#define EE   262144
#define CC   256
#define HH   4
#define DHH  64

typedef __bf16 bf16;
typedef __bf16 bf16x8 __attribute__((ext_vector_type(8)));
typedef float  f32x4  __attribute__((ext_vector_type(4)));

static __device__ __forceinline__ bf16 f2bf(float f) { return (bf16)f; }

// ---------------------------------------------------------------- conversions
__global__ void cvt_f32_bf16(const float* __restrict__ in, bf16* __restrict__ out, int n) {
    for (int i = blockIdx.x * blockDim.x + threadIdx.x; i < n; i += gridDim.x * blockDim.x)
        out[i] = f2bf(in[i]);
}

// weight_local [K=256][N=256] row-major -> wlT [N][K] bf16
__global__ void transpose_cvt(const float* __restrict__ in, bf16* __restrict__ out) {
    int n = blockIdx.x;       // output row
    int k = threadIdx.x;      // output col
    out[n * 256 + k] = f2bf(in[k * 256 + n]);
}

// ---------------------------------------------------------------- GCN conv
__global__ void degree_k(const int* __restrict__ adj, float* __restrict__ deg) {
    int e = blockIdx.x * 256 + threadIdx.x;
    if (e < EE) atomicAdd(&deg[adj[EE + e]], 1.0f);
}

// one 256-thread block per edge (grid-stride over edges); thread = channel
__global__ void gcn_scatter(const float* __restrict__ x, const int* __restrict__ adj,
                            const float* __restrict__ deg, float* __restrict__ hi) {
    for (int e = blockIdx.x; e < EE; e += gridDim.x) {
        int row = adj[e];
        int col = adj[EE + e];
        float prod = deg[col] * deg[row];
        float val = (prod > 0.f) ? rsqrtf(prod) : 0.f;
        int t = threadIdx.x;
        atomicAdd(&hi[(size_t)col * CC + t], x[(size_t)row * CC + t] * val);
    }
}

// ---------------------------------------------------------------- BT GEMM
// C[M,N] = A[M,K] * W[N,K]^T (+bias).  A,W bf16 row-major.  K%64==0, M%128==0, N%64==0.
__global__ __launch_bounds__(256) void gemm_bt(
        const bf16* __restrict__ A, const bf16* __restrict__ W,
        const float* __restrict__ bias,
        float* __restrict__ outF, bf16* __restrict__ outB,
        int M, int N, int K) {
    const int tid  = threadIdx.x;
    const int wave = tid >> 6;
    const int lane = tid & 63;
    const int quad = lane >> 4;
    const int l15  = lane & 15;
    const int m0 = blockIdx.x * 128;
    const int n0 = blockIdx.y * 64;

    __shared__ bf16 Alds[128][72];
    __shared__ bf16 Wlds[64][72];

    f32x4 acc[2][4];
    #pragma unroll
    for (int mt = 0; mt < 2; mt++)
        #pragma unroll
        for (int nt = 0; nt < 4; nt++)
            acc[mt][nt] = (f32x4){0.f, 0.f, 0.f, 0.f};

    for (int k0 = 0; k0 < K; k0 += 64) {
        // stage A tile 128x64
        #pragma unroll
        for (int i = 0; i < 4; i++) {
            int u = tid + i * 256;          // 0..1023
            int r = u >> 3;
            int cp = u & 7;
            *reinterpret_cast<bf16x8*>(&Alds[r][cp * 8]) =
                *reinterpret_cast<const bf16x8*>(A + (size_t)(m0 + r) * K + k0 + cp * 8);
        }
        // stage W tile 64x64
        #pragma unroll
        for (int i = 0; i < 2; i++) {
            int u = tid + i * 256;          // 0..511
            int r = u >> 3;
            int cp = u & 7;
            *reinterpret_cast<bf16x8*>(&Wlds[r][cp * 8]) =
                *reinterpret_cast<const bf16x8*>(W + (size_t)(n0 + r) * K + k0 + cp * 8);
        }
        __syncthreads();
        #pragma unroll
        for (int c = 0; c < 2; c++) {
            bf16x8 af[2], wf[4];
            #pragma unroll
            for (int mt = 0; mt < 2; mt++)
                af[mt] = *reinterpret_cast<const bf16x8*>(&Alds[wave * 32 + mt * 16 + l15][c * 32 + quad * 8]);
            #pragma unroll
            for (int nt = 0; nt < 4; nt++)
                wf[nt] = *reinterpret_cast<const bf16x8*>(&Wlds[nt * 16 + l15][c * 32 + quad * 8]);
            #pragma unroll
            for (int mt = 0; mt < 2; mt++)
                #pragma unroll
                for (int nt = 0; nt < 4; nt++)
                    acc[mt][nt] = __builtin_amdgcn_mfma_f32_16x16x32_bf16(af[mt], wf[nt], acc[mt][nt], 0, 0, 0);
        }
        __syncthreads();
    }
    // epilogue: C/D layout col=lane&15, row=quad*4+reg
    #pragma unroll
    for (int mt = 0; mt < 2; mt++)
        #pragma unroll
        for (int nt = 0; nt < 4; nt++)
            #pragma unroll
            for (int r = 0; r < 4; r++) {
                int m = m0 + wave * 32 + mt * 16 + quad * 4 + r;
                int n = n0 + nt * 16 + l15;
                float v = acc[mt][nt][r];
                if (bias) v += bias[n];
                if (outF) outF[(size_t)m * N + n] = v;
                else      outB[(size_t)m * N + n] = f2bf(v);
            }
}

// ---------------------------------------------------------------- flash attention
// qkv [N,768] bf16 (q|k|v each 256 = 4 heads x 64). attnO [N,256] bf16.
// grid (N/64, H), block 256 (4 waves); wave handles 16 q rows.
__global__ __launch_bounds__(256) void flash_attn(const bf16* __restrict__ qkv,
                                                  bf16* __restrict__ attnO) {
    const int tid  = threadIdx.x;
    const int wave = tid >> 6;
    const int lane = tid & 63;
    const int quad = lane >> 4;
    const int l15  = lane & 15;
    const int h     = blockIdx.y;
    const int qbase = blockIdx.x * 64;

    __shared__ bf16 Klds[64][72];       // [key][d]
    __shared__ bf16 Vtlds[64][72];      // [d][key]
    __shared__ bf16 Plds[4][16][72];    // per-wave [qrow][key]

    // preload Q fragments (A layout: m=lane&15, k=quad*8+j per 32-chunk)
    const int qrow = qbase + wave * 16 + l15;
    bf16x8 qf[2];
    #pragma unroll
    for (int c = 0; c < 2; c++)
        qf[c] = *reinterpret_cast<const bf16x8*>(qkv + (size_t)qrow * 768 + h * 64 + c * 32 + quad * 8);

    f32x4 oacc[4];
    #pragma unroll
    for (int nt = 0; nt < 4; nt++) oacc[nt] = (f32x4){0.f, 0.f, 0.f, 0.f};
    float m_run[4], l_run[4];
    #pragma unroll
    for (int r = 0; r < 4; r++) { m_run[r] = -INFINITY; l_run[r] = 0.f; }

    for (int kt = 0; kt < NN / 64; kt++) {
        __syncthreads();   // prior iteration's PV reads done before restage
        #pragma unroll
        for (int i = 0; i < 2; i++) {
            int u = tid + i * 256;       // 0..511
            int key = u >> 3;
            int dp  = u & 7;
            const bf16* kp = qkv + (size_t)(kt * 64 + key) * 768 + 256 + h * 64 + dp * 8;
            *reinterpret_cast<bf16x8*>(&Klds[key][dp * 8]) = *reinterpret_cast<const bf16x8*>(kp);
            const bf16* vp = qkv + (size_t)(kt * 64 + key) * 768 + 512 + h * 64 + dp * 8;
            bf16x8 vv = *reinterpret_cast<const bf16x8*>(vp);
            #pragma unroll
            for (int j = 0; j < 8; j++) Vtlds[dp * 8 + j][key] = vv[j];
        }
        __syncthreads();

        // S = Q K^T  (16q x 64k per wave)
        f32x4 sacc[4];
        #pragma unroll
        for (int nt = 0; nt < 4; nt++) sacc[nt] = (f32x4){0.f, 0.f, 0.f, 0.f};
        #pragma unroll
        for (int c = 0; c < 2; c++)
            #pragma unroll
            for (int nt = 0; nt < 4; nt++) {
                bf16x8 kf = *reinterpret_cast<const bf16x8*>(&Klds[nt * 16 + l15][c * 32 + quad * 8]);
                sacc[nt] = __builtin_amdgcn_mfma_f32_16x16x32_bf16(qf[c], kf, sacc[nt], 0, 0, 0);
            }

        // online softmax; row = quad*4 + r, cols spread over 16 lanes x 4 n-tiles
        float p[4][4];
        #pragma unroll
        for (int r = 0; r < 4; r++) {
            float tmax = -INFINITY;
            #pragma unroll
            for (int nt = 0; nt < 4; nt++) {
                float s = sacc[nt][r] * 0.125f;   // 1/sqrt(64)
                p[nt][r] = s;
                tmax = fmaxf(tmax, s);
            }
            #pragma unroll
            for (int off = 8; off > 0; off >>= 1) tmax = fmaxf(tmax, __shfl_xor(tmax, off));
            float mnew = fmaxf(m_run[r], tmax);
            float al = __expf(m_run[r] - mnew);
            float rs = 0.f;
            #pragma unroll
            for (int nt = 0; nt < 4; nt++) {
                float pv = __expf(p[nt][r] - mnew);
                p[nt][r] = pv;
                rs += pv;
            }
            #pragma unroll
            for (int off = 8; off > 0; off >>= 1) rs += __shfl_xor(rs, off);
            l_run[r] = l_run[r] * al + rs;
            m_run[r] = mnew;
            #pragma unroll
            for (int nt = 0; nt < 4; nt++) oacc[nt][r] *= al;
        }

        // P -> LDS (C-layout write) then reread as A-layout
        #pragma unroll
        for (int r = 0; r < 4; r++)
            #pragma unroll
            for (int nt = 0; nt < 4; nt++)
                Plds[wave][quad * 4 + r][nt * 16 + l15] = f2bf(p[nt][r]);
        __syncthreads();

        // O += P V
        #pragma unroll
        for (int c = 0; c < 2; c++) {
            bf16x8 pf = *reinterpret_cast<const bf16x8*>(&Plds[wave][l15][c * 32 + quad * 8]);
            #pragma unroll
            for (int nt = 0; nt < 4; nt++) {
                bf16x8 vf = *reinterpret_cast<const bf16x8*>(&Vtlds[nt * 16 + l15][c * 32 + quad * 8]);
                oacc[nt] = __builtin_amdgcn_mfma_f32_16x16x32_bf16(pf, vf, oacc[nt], 0, 0, 0);
            }
        }
    }

    #pragma unroll
    for (int nt = 0; nt < 4; nt++)
        #pragma unroll
        for (int r = 0; r < 4; r++) {
            int q = qbase + wave * 16 + quad * 4 + r;
            float o = oacc[nt][r] / l_run[r];
            attnO[(size_t)q * CC + h * 64 + nt * 16 + l15] = f2bf(o);
        }
}

// ---------------------------------------------------------------- LN + combine
// combined = w*local + (1-w)*LayerNorm(x + attn_proj); one block per row
__global__ __launch_bounds__(256) void ln_combine(
        const float* __restrict__ x, const float* __restrict__ aproj,
        const float* __restrict__ local,
        const float* __restrict__ g, const float* __restrict__ b,
        const float* __restrict__ alpha_p, bf16* __restrict__ comb) {
    int row = blockIdx.x;
    int t = threadIdx.x;
    __shared__ float red[256];
    float v = x[(size_t)row * CC + t] + aproj[(size_t)row * CC + t];
    red[t] = v;
    __syncthreads();
    for (int s = 128; s > 0; s >>= 1) { if (t < s) red[t] += red[t + s]; __syncthreads(); }
    float mu = red[0] * (1.f / CC);
    __syncthreads();
    float d = v - mu;
    red[t] = d * d;
    __syncthreads();
    for (int s = 128; s > 0; s >>= 1) { if (t < s) red[t] += red[t + s]; __syncthreads(); }
    float var = red[0] * (1.f / CC);
    float rstd = rsqrtf(var + 1e-5f);
    float ln = d * rstd * g[t] + b[t];
    float w = 1.f / (1.f + __expf(-alpha_p[0]));
    comb[(size_t)row * CC + t] = f2bf(w * local[(size_t)row * CC + t] + (1.f - w) * ln);
}

// ---------------------------------------------------------------- launch
extern "C" void kernel_launch(void* const* d_in, const int* in_sizes, int n_in,
                              void* d_out, int out_size, void* d_ws, size_t ws_size,
                              hipStream_t stream) {
    (void)in_sizes; (void)n_in; (void)out_size; (void)ws_size;
    const float* x    = (const float*)d_in[0];
    const int*   adj  = (const int*)d_in[1];
    const float* wloc = (const float*)d_in[2];
    const float* ipw  = (const float*)d_in[3];
    const float* ipb  = (const float*)d_in[4];
    const float* opw  = (const float*)d_in[5];
    const float* opb  = (const float*)d_in[6];
    const float* lng  = (const float*)d_in[7];
    const float* lnb  = (const float*)d_in[8];
    const float* alp  = (const float*)d_in[9];
    const float* fcw  = (const float*)d_in[10];
    const float* fcb  = (const float*)d_in[11];
    float* out = (float*)d_out;

    char* p = (char*)d_ws;
    float* deg  = (float*)p;  p += (size_t)NN * 4;
    float* hi   = (float*)p;  p += (size_t)NN * CC * 4;
    bf16* xb    = (bf16*)p;   p += (size_t)NN * CC * 2;
    bf16* hib   = (bf16*)p;   p += (size_t)NN * CC * 2;
    bf16* ipwb  = (bf16*)p;   p += (size_t)768 * 256 * 2;
    bf16* wlTb  = (bf16*)p;   p += (size_t)256 * 256 * 2;
    bf16* opwb  = (bf16*)p;   p += (size_t)256 * 256 * 2;
    bf16* fcwb  = (bf16*)p;   p += (size_t)256 * 256 * 2;
    bf16* qkvb  = (bf16*)p;   p += (size_t)NN * 768 * 2;
    bf16* aOb   = (bf16*)p;   p += (size_t)NN * CC * 2;
    float* aprj = (float*)p;  p += (size_t)NN * CC * 4;
    float* locl = (float*)p;  p += (size_t)NN * CC * 4;
    bf16* comb  = (bf16*)p;   p += (size_t)NN * CC * 2;

    // zero deg + hi (atomic accumulators)
    hipMemsetAsync(d_ws, 0, (size_t)NN * 4 + (size_t)NN * CC * 4, stream);

    cvt_f32_bf16<<<2048, 256, 0, stream>>>(x, xb, NN * CC);
    cvt_f32_bf16<<<768, 256, 0, stream>>>(ipw, ipwb, 768 * 256);
    cvt_f32_bf16<<<256, 256, 0, stream>>>(opw, opwb, 256 * 256);
    cvt_f32_bf16<<<256, 256, 0, stream>>>(fcw, fcwb, 256 * 256);
    transpose_cvt<<<256, 256, 0, stream>>>(wloc, wlTb);

    degree_k<<<EE / 256, 256, 0, stream>>>(adj, deg);
    gcn_scatter<<<16384, 256, 0, stream>>>(x, adj, deg, hi);
    cvt_f32_bf16<<<2048, 256, 0, stream>>>(hi, hib, NN * CC);

    // qkv = x @ in_proj_w.T + b  -> bf16
    gemm_bt<<<dim3(NN / 128, 768 / 64), 256, 0, stream>>>(xb, ipwb, ipb, nullptr, qkvb, NN, 768, 256);
    flash_attn<<<dim3(NN / 64, HH), 256, 0, stream>>>(qkvb, aOb);
    // attn_proj = attnO @ out_proj_w.T + b -> f32
    gemm_bt<<<dim3(NN / 128, 256 / 64), 256, 0, stream>>>(aOb, opwb, opb, aprj, nullptr, NN, 256, 256);
    // local = hi @ weight_local -> f32
    gemm_bt<<<dim3(NN / 128, 256 / 64), 256, 0, stream>>>(hib, wlTb, nullptr, locl, nullptr, NN, 256, 256);
    ln_combine<<<NN, 256, 0, stream>>>(x, aprj, locl, lng, lnb, alp, comb);
    // out = combined @ fc_w.T + fc_b -> f32
    gemm_bt<<<dim3(NN / 128, 256 / 64), 256, 0, stream>>>(comb, fcwb, fcb, out, nullptr, NN, 256, 256);
}

// Round 2
// 544.703 us; speedup vs baseline: 1.4035x; 1.4035x over previous
//
#include <hip/hip_runtime.h>
#include <hip/hip_bf16.h>
#include <math.h>

#define NN   8192
#define EE   262144
#define CC   256
#define HH   4
#define DHH  64

typedef __bf16 bf16;
typedef __bf16 bf16x8 __attribute__((ext_vector_type(8)));
typedef float  f32x4  __attribute__((ext_vector_type(4)));

static __device__ __forceinline__ bf16 f2bf(float f) { return (bf16)f; }

// ---------------------------------------------------------------- conversions
__global__ void cvt_f32_bf16(const float* __restrict__ in, bf16* __restrict__ out, int n) {
    for (int i = blockIdx.x * blockDim.x + threadIdx.x; i < n; i += gridDim.x * blockDim.x)
        out[i] = f2bf(in[i]);
}

// weight_local [K=256][N=256] row-major -> wlT [N][K] bf16
__global__ void transpose_cvt(const float* __restrict__ in, bf16* __restrict__ out) {
    int n = blockIdx.x;
    int k = threadIdx.x;
    out[n * 256 + k] = f2bf(in[k * 256 + n]);
}

// V section of qkv [N,768] -> vT[c=h*64+d][N]  (c in [0,256))
__global__ void build_vT(const bf16* __restrict__ qkv, bf16* __restrict__ vT) {
    __shared__ bf16 tl[64][72];
    const int n0 = blockIdx.x * 64;
    const int c0 = blockIdx.y * 64;
    const int tid = threadIdx.x;
    #pragma unroll
    for (int i = 0; i < 2; i++) {
        int u = tid + i * 256;              // 0..511
        int n = u >> 3, c8 = (u & 7) * 8;
        *reinterpret_cast<bf16x8*>(&tl[n][c8]) =
            *reinterpret_cast<const bf16x8*>(qkv + (size_t)(n0 + n) * 768 + 512 + c0 + c8);
    }
    __syncthreads();
    #pragma unroll
    for (int i = 0; i < 2; i++) {
        int u = tid + i * 256;
        int c = u >> 3, n8 = (u & 7) * 8;
        bf16x8 v;
        #pragma unroll
        for (int j = 0; j < 8; j++) v[j] = tl[n8 + j][c];
        *reinterpret_cast<bf16x8*>(vT + (size_t)(c0 + c) * 8192 + n0 + n8) = v;
    }
}

// ---------------------------------------------------------------- GCN conv
__global__ void degree_k(const int* __restrict__ adj, float* __restrict__ deg) {
    int e = blockIdx.x * 256 + threadIdx.x;
    if (e < EE) atomicAdd(&deg[adj[EE + e]], 1.0f);
}

__global__ void gcn_scatter(const float* __restrict__ x, const int* __restrict__ adj,
                            const float* __restrict__ deg, float* __restrict__ hi) {
    for (int e = blockIdx.x; e < EE; e += gridDim.x) {
        int row = adj[e];
        int col = adj[EE + e];
        float prod = deg[col] * deg[row];
        float val = (prod > 0.f) ? rsqrtf(prod) : 0.f;
        int t = threadIdx.x;
        atomicAdd(&hi[(size_t)col * CC + t], x[(size_t)row * CC + t] * val);
    }
}

// ---------------------------------------------------------------- BT GEMM
// C[M,N] = A[M,K] * W[N,K]^T (+bias).  A,W bf16 row-major.
__global__ __launch_bounds__(256) void gemm_bt(
        const bf16* __restrict__ A, const bf16* __restrict__ W,
        const float* __restrict__ bias,
        float* __restrict__ outF, bf16* __restrict__ outB,
        int M, int N, int K) {
    const int tid  = threadIdx.x;
    const int wave = tid >> 6;
    const int lane = tid & 63;
    const int quad = lane >> 4;
    const int l15  = lane & 15;
    const int m0 = blockIdx.x * 128;
    const int n0 = blockIdx.y * 64;

    __shared__ bf16 Alds[128][72];
    __shared__ bf16 Wlds[64][72];

    f32x4 acc[2][4];
    #pragma unroll
    for (int mt = 0; mt < 2; mt++)
        #pragma unroll
        for (int nt = 0; nt < 4; nt++)
            acc[mt][nt] = (f32x4){0.f, 0.f, 0.f, 0.f};

    for (int k0 = 0; k0 < K; k0 += 64) {
        #pragma unroll
        for (int i = 0; i < 4; i++) {
            int u = tid + i * 256;
            int r = u >> 3;
            int cp = u & 7;
            *reinterpret_cast<bf16x8*>(&Alds[r][cp * 8]) =
                *reinterpret_cast<const bf16x8*>(A + (size_t)(m0 + r) * K + k0 + cp * 8);
        }
        #pragma unroll
        for (int i = 0; i < 2; i++) {
            int u = tid + i * 256;
            int r = u >> 3;
            int cp = u & 7;
            *reinterpret_cast<bf16x8*>(&Wlds[r][cp * 8]) =
                *reinterpret_cast<const bf16x8*>(W + (size_t)(n0 + r) * K + k0 + cp * 8);
        }
        __syncthreads();
        #pragma unroll
        for (int c = 0; c < 2; c++) {
            bf16x8 af[2], wf[4];
            #pragma unroll
            for (int mt = 0; mt < 2; mt++)
                af[mt] = *reinterpret_cast<const bf16x8*>(&Alds[wave * 32 + mt * 16 + l15][c * 32 + quad * 8]);
            #pragma unroll
            for (int nt = 0; nt < 4; nt++)
                wf[nt] = *reinterpret_cast<const bf16x8*>(&Wlds[nt * 16 + l15][c * 32 + quad * 8]);
            #pragma unroll
            for (int mt = 0; mt < 2; mt++)
                #pragma unroll
                for (int nt = 0; nt < 4; nt++)
                    acc[mt][nt] = __builtin_amdgcn_mfma_f32_16x16x32_bf16(af[mt], wf[nt], acc[mt][nt], 0, 0, 0);
        }
        __syncthreads();
    }
    #pragma unroll
    for (int mt = 0; mt < 2; mt++)
        #pragma unroll
        for (int nt = 0; nt < 4; nt++)
            #pragma unroll
            for (int r = 0; r < 4; r++) {
                int m = m0 + wave * 32 + mt * 16 + quad * 4 + r;
                int n = n0 + nt * 16 + l15;
                float v = acc[mt][nt][r];
                if (bias) v += bias[n];
                if (outF) outF[(size_t)m * N + n] = v;
                else      outB[(size_t)m * N + n] = f2bf(v);
            }
}

// ---------------------------------------------------------------- flash attention v2
// S^T trick: S^T = K.Q^T so softmax state is per-lane (q = lane&15, 2 shuffles);
// permuted key rows make exp'd S^T registers the exact A-operand for PV mfma.
// qkv [N,768] bf16; vT [256][8192] bf16 (row h*64+d); attnO [N,256] bf16.
// grid 512: h = bx&3 (XCD k serves head k&3 -> K/V L2 locality), qb = bx>>2.
__global__ __launch_bounds__(256, 4) void flash_attn2(const bf16* __restrict__ qkv,
                                                      const bf16* __restrict__ vT,
                                                      bf16* __restrict__ attnO) {
    const int tid  = threadIdx.x;
    const int wave = tid >> 6;
    const int lane = tid & 63;
    const int quad = lane >> 4;
    const int l15  = lane & 15;
    const int bx = blockIdx.x;
    const int h  = bx & 3;
    const int qb = bx >> 2;            // 0..127
    const int qbase = qb * 64;

    __shared__ bf16 Klds[2][64][64];   // [buf][key][d], granule-swizzled
    __shared__ bf16 Vlds[2][64][64];   // [buf][d][key], granule-swizzled

    // Q fragments (B operand: n=q=l15, k=d=quad*8+j), prescaled by 1/8 (exact)
    const int qrow = qbase + wave * 16 + l15;
    bf16x8 qf[2];
    #pragma unroll
    for (int c = 0; c < 2; c++) {
        bf16x8 raw = *reinterpret_cast<const bf16x8*>(qkv + (size_t)qrow * 768 + h * 64 + c * 32 + quad * 8);
        #pragma unroll
        for (int j = 0; j < 8; j++) qf[c][j] = f2bf((float)raw[j] * 0.125f);
    }

    // QK A-operand rows: K_phys(t, m=l15) = 32*(t>>1) + 8*(l15>>2) + 4*(t&1) + (l15&3)
    // -> C row quad*4+r holds key 32c + 8*quad + 4s + r  (exact PV A-layout after pack)
    int koff[4][2], voff[4][2];
    #pragma unroll
    for (int t = 0; t < 4; t++) {
        int kr = 32 * (t >> 1) + 8 * (l15 >> 2) + 4 * (t & 1) + (l15 & 3);
        int fk = ((kr >> 3) & 3) + ((kr & 2) << 1);          // K swizzle
        #pragma unroll
        for (int c = 0; c < 2; c++)
            koff[t][c] = kr * 64 + ((((c * 4 + quad) ^ fk)) << 3);
        int dd = t * 16 + l15;                               // t doubles as nt for V
        #pragma unroll
        for (int c = 0; c < 2; c++)
            voff[t][c] = dd * 64 + ((((c * 4 + quad) ^ (dd & 7))) << 3);
    }

    // staging offsets (thread covers 2 chunks of each tile)
    int srcK[2], srcV[2], dstK[2], dstV[2];
    #pragma unroll
    for (int i = 0; i < 2; i++) {
        int u = tid + i * 256;
        int r = u >> 3, g = u & 7;
        int fk = ((r >> 3) & 3) + ((r & 2) << 1);
        dstK[i] = r * 64 + ((g ^ fk) << 3);
        dstV[i] = r * 64 + ((g ^ (r & 7)) << 3);
        srcK[i] = r * 768 + 256 + h * 64 + g * 8;   // + key0*768
        srcV[i] = (h * 64 + r) * 8192 + g * 8;      // + key0
    }

    f32x4 oacc[4];
    #pragma unroll
    for (int nt = 0; nt < 4; nt++) oacc[nt] = (f32x4){0.f, 0.f, 0.f, 0.f};
    float m_run = -INFINITY, l_run = 0.f;

    // prologue: stage tile 0 into buf 0
    #pragma unroll
    for (int i = 0; i < 2; i++) {
        bf16x8 kv = *reinterpret_cast<const bf16x8*>(qkv + srcK[i]);
        bf16x8 vv = *reinterpret_cast<const bf16x8*>(vT + srcV[i]);
        *reinterpret_cast<bf16x8*>(&Klds[0][0][0] + dstK[i]) = kv;
        *reinterpret_cast<bf16x8*>(&Vlds[0][0][0] + dstV[i]) = vv;
    }
    __syncthreads();

    for (int kt = 0; kt < 128; kt++) {
        const int p = kt & 1;
        bf16x8 stK[2], stV[2];
        if (kt < 127) {
            #pragma unroll
            for (int i = 0; i < 2; i++) {
                stK[i] = *reinterpret_cast<const bf16x8*>(qkv + (size_t)(kt + 1) * 64 * 768 + srcK[i]);
                stV[i] = *reinterpret_cast<const bf16x8*>(vT + (kt + 1) * 64 + srcV[i]);
            }
        }
        const bf16* Kb = &Klds[p][0][0];
        const bf16* Vb = &Vlds[p][0][0];

        // S^T = K . Q^T
        f32x4 sacc[4];
        #pragma unroll
        for (int t = 0; t < 4; t++) sacc[t] = (f32x4){0.f, 0.f, 0.f, 0.f};
        #pragma unroll
        for (int c = 0; c < 2; c++)
            #pragma unroll
            for (int t = 0; t < 4; t++) {
                bf16x8 af = *reinterpret_cast<const bf16x8*>(Kb + koff[t][c]);
                sacc[t] = __builtin_amdgcn_mfma_f32_16x16x32_bf16(af, qf[c], sacc[t], 0, 0, 0);
            }

        // online softmax; q = l15 per lane, keys across regs + quads
        float tmax = -INFINITY;
        #pragma unroll
        for (int t = 0; t < 4; t++)
            #pragma unroll
            for (int r = 0; r < 4; r++) tmax = fmaxf(tmax, sacc[t][r]);
        tmax = fmaxf(tmax, __shfl_xor(tmax, 16));
        tmax = fmaxf(tmax, __shfl_xor(tmax, 32));
        float mnew = fmaxf(m_run, tmax);
        float al = __expf(m_run - mnew);
        float rs = 0.f;
        bf16x8 pf[2];
        #pragma unroll
        for (int t = 0; t < 4; t++)
            #pragma unroll
            for (int r = 0; r < 4; r++) {
                float pv = __expf(sacc[t][r] - mnew);
                rs += pv;
                pf[t >> 1][(t & 1) * 4 + r] = f2bf(pv);
            }
        rs += __shfl_xor(rs, 16);
        rs += __shfl_xor(rs, 32);
        l_run = l_run * al + rs;
        m_run = mnew;

        // O rescale: row q = quad*4+r; al lives at lane q
        #pragma unroll
        for (int r = 0; r < 4; r++) {
            float ar = __shfl(al, quad * 4 + r);
            #pragma unroll
            for (int nt = 0; nt < 4; nt++) oacc[nt][r] *= ar;
        }

        // O += P.V  (P direct from regs; B = vT rows)
        #pragma unroll
        for (int c = 0; c < 2; c++)
            #pragma unroll
            for (int nt = 0; nt < 4; nt++) {
                bf16x8 bfv = *reinterpret_cast<const bf16x8*>(Vb + voff[nt][c]);
                oacc[nt] = __builtin_amdgcn_mfma_f32_16x16x32_bf16(pf[c], bfv, oacc[nt], 0, 0, 0);
            }

        if (kt < 127) {
            bf16* Kb1 = &Klds[p ^ 1][0][0];
            bf16* Vb1 = &Vlds[p ^ 1][0][0];
            #pragma unroll
            for (int i = 0; i < 2; i++) {
                *reinterpret_cast<bf16x8*>(Kb1 + dstK[i]) = stK[i];
                *reinterpret_cast<bf16x8*>(Vb1 + dstV[i]) = stV[i];
            }
        }
        __syncthreads();
    }

    float linv = 1.f / l_run;
    #pragma unroll
    for (int r = 0; r < 4; r++) {
        float lr = __shfl(linv, quad * 4 + r);
        int q = qbase + wave * 16 + quad * 4 + r;
        #pragma unroll
        for (int nt = 0; nt < 4; nt++)
            attnO[(size_t)q * CC + h * 64 + nt * 16 + l15] = f2bf(oacc[nt][r] * lr);
    }
}

// ---------------------------------------------------------------- LN + combine
__global__ __launch_bounds__(256) void ln_combine(
        const float* __restrict__ x, const float* __restrict__ aproj,
        const float* __restrict__ local,
        const float* __restrict__ g, const float* __restrict__ b,
        const float* __restrict__ alpha_p, bf16* __restrict__ comb) {
    int row = blockIdx.x;
    int t = threadIdx.x;
    __shared__ float red[256];
    float v = x[(size_t)row * CC + t] + aproj[(size_t)row * CC + t];
    red[t] = v;
    __syncthreads();
    for (int s = 128; s > 0; s >>= 1) { if (t < s) red[t] += red[t + s]; __syncthreads(); }
    float mu = red[0] * (1.f / CC);
    __syncthreads();
    float d = v - mu;
    red[t] = d * d;
    __syncthreads();
    for (int s = 128; s > 0; s >>= 1) { if (t < s) red[t] += red[t + s]; __syncthreads(); }
    float var = red[0] * (1.f / CC);
    float rstd = rsqrtf(var + 1e-5f);
    float ln = d * rstd * g[t] + b[t];
    float w = 1.f / (1.f + __expf(-alpha_p[0]));
    comb[(size_t)row * CC + t] = f2bf(w * local[(size_t)row * CC + t] + (1.f - w) * ln);
}

// ---------------------------------------------------------------- launch
extern "C" void kernel_launch(void* const* d_in, const int* in_sizes, int n_in,
                              void* d_out, int out_size, void* d_ws, size_t ws_size,
                              hipStream_t stream) {
    (void)in_sizes; (void)n_in; (void)out_size; (void)ws_size;
    const float* x    = (const float*)d_in[0];
    const int*   adj  = (const int*)d_in[1];
    const float* wloc = (const float*)d_in[2];
    const float* ipw  = (const float*)d_in[3];
    const float* ipb  = (const float*)d_in[4];
    const float* opw  = (const float*)d_in[5];
    const float* opb  = (const float*)d_in[6];
    const float* lng  = (const float*)d_in[7];
    const float* lnb  = (const float*)d_in[8];
    const float* alp  = (const float*)d_in[9];
    const float* fcw  = (const float*)d_in[10];
    const float* fcb  = (const float*)d_in[11];
    float* out = (float*)d_out;

    char* p = (char*)d_ws;
    float* deg  = (float*)p;  p += (size_t)NN * 4;
    float* hi   = (float*)p;  p += (size_t)NN * CC * 4;
    bf16* xb    = (bf16*)p;   p += (size_t)NN * CC * 2;
    bf16* hib   = (bf16*)p;   p += (size_t)NN * CC * 2;
    bf16* ipwb  = (bf16*)p;   p += (size_t)768 * 256 * 2;
    bf16* wlTb  = (bf16*)p;   p += (size_t)256 * 256 * 2;
    bf16* opwb  = (bf16*)p;   p += (size_t)256 * 256 * 2;
    bf16* fcwb  = (bf16*)p;   p += (size_t)256 * 256 * 2;
    bf16* qkvb  = (bf16*)p;   p += (size_t)NN * 768 * 2;
    bf16* aOb   = (bf16*)p;   p += (size_t)NN * CC * 2;
    float* aprj = (float*)p;  p += (size_t)NN * CC * 4;
    float* locl = (float*)p;  p += (size_t)NN * CC * 4;
    bf16* comb  = (bf16*)p;   p += (size_t)NN * CC * 2;
    // vT (4 MB) aliases hi (8 MB): hi's last read (cvt to hib) precedes build_vT
    bf16* vT = (bf16*)hi;

    hipMemsetAsync(d_ws, 0, (size_t)NN * 4 + (size_t)NN * CC * 4, stream);

    cvt_f32_bf16<<<2048, 256, 0, stream>>>(x, xb, NN * CC);
    cvt_f32_bf16<<<768, 256, 0, stream>>>(ipw, ipwb, 768 * 256);
    cvt_f32_bf16<<<256, 256, 0, stream>>>(opw, opwb, 256 * 256);
    cvt_f32_bf16<<<256, 256, 0, stream>>>(fcw, fcwb, 256 * 256);
    transpose_cvt<<<256, 256, 0, stream>>>(wloc, wlTb);

    degree_k<<<EE / 256, 256, 0, stream>>>(adj, deg);
    gcn_scatter<<<16384, 256, 0, stream>>>(x, adj, deg, hi);
    cvt_f32_bf16<<<2048, 256, 0, stream>>>(hi, hib, NN * CC);

    gemm_bt<<<dim3(NN / 128, 768 / 64), 256, 0, stream>>>(xb, ipwb, ipb, nullptr, qkvb, NN, 768, 256);
    build_vT<<<dim3(NN / 64, 4), 256, 0, stream>>>(qkvb, vT);
    flash_attn2<<<512, 256, 0, stream>>>(qkvb, vT, aOb);
    gemm_bt<<<dim3(NN / 128, 256 / 64), 256, 0, stream>>>(aOb, opwb, opb, aprj, nullptr, NN, 256, 256);
    gemm_bt<<<dim3(NN / 128, 256 / 64), 256, 0, stream>>>(hib, wlTb, nullptr, locl, nullptr, NN, 256, 256);
    ln_combine<<<NN, 256, 0, stream>>>(x, aprj, locl, lng, lnb, alp, comb);
    gemm_bt<<<dim3(NN / 128, 256 / 64), 256, 0, stream>>>(comb, fcwb, fcb, out, nullptr, NN, 256, 256);
}

// Round 3
// 343.917 us; speedup vs baseline: 2.2229x; 1.5838x over previous
//
#include <hip/hip_runtime.h>
#include <hip/hip_bf16.h>
#include <math.h>

#define NN   8192
#define EE   262144
#define CC   256
#define HH   4
#define DHH  64

typedef __bf16 bf16;
typedef __bf16 bf16x8 __attribute__((ext_vector_type(8)));
typedef float  f32x4  __attribute__((ext_vector_type(4)));

static __device__ __forceinline__ bf16 f2bf(float f) { return (bf16)f; }

// ---------------------------------------------------------------- conversions
__global__ void cvt_f32_bf16(const float* __restrict__ in, bf16* __restrict__ out, int n) {
    for (int i = blockIdx.x * blockDim.x + threadIdx.x; i < n; i += gridDim.x * blockDim.x)
        out[i] = f2bf(in[i]);
}

// weight_local [K=256][N=256] row-major -> wlT [N][K] bf16
__global__ void transpose_cvt(const float* __restrict__ in, bf16* __restrict__ out) {
    int n = blockIdx.x;
    int k = threadIdx.x;
    out[n * 256 + k] = f2bf(in[k * 256 + n]);
}

// V section of qkv [N,768] -> vT[c=h*64+d][N]  (c in [0,256))
__global__ void build_vT(const bf16* __restrict__ qkv, bf16* __restrict__ vT) {
    __shared__ bf16 tl[64][72];
    const int n0 = blockIdx.x * 64;
    const int c0 = blockIdx.y * 64;
    const int tid = threadIdx.x;
    #pragma unroll
    for (int i = 0; i < 2; i++) {
        int u = tid + i * 256;
        int n = u >> 3, c8 = (u & 7) * 8;
        *reinterpret_cast<bf16x8*>(&tl[n][c8]) =
            *reinterpret_cast<const bf16x8*>(qkv + (size_t)(n0 + n) * 768 + 512 + c0 + c8);
    }
    __syncthreads();
    #pragma unroll
    for (int i = 0; i < 2; i++) {
        int u = tid + i * 256;
        int c = u >> 3, n8 = (u & 7) * 8;
        bf16x8 v;
        #pragma unroll
        for (int j = 0; j < 8; j++) v[j] = tl[n8 + j][c];
        *reinterpret_cast<bf16x8*>(vT + (size_t)(c0 + c) * 8192 + n0 + n8) = v;
    }
}

// ---------------------------------------------------------------- GCN conv (CSR gather)
__global__ void degree_i(const int* __restrict__ adj, int* __restrict__ ideg) {
    int e = blockIdx.x * 256 + threadIdx.x;
    if (e < EE) atomicAdd(&ideg[adj[EE + e]], 1);
}

// single block: exclusive scan over 8192 degrees -> off[8193], cursor, rs=1/sqrt(deg)
__global__ __launch_bounds__(256) void scan_offsets(const int* __restrict__ ideg,
        int* __restrict__ off, int* __restrict__ cursor, float* __restrict__ rs) {
    __shared__ int ps[256];
    const int tid = threadIdx.x;
    const int base = tid * 32;
    int loc[32];
    int s = 0;
    #pragma unroll
    for (int i = 0; i < 32; i++) { loc[i] = s; s += ideg[base + i]; }
    ps[tid] = s;
    __syncthreads();
    for (int d = 1; d < 256; d <<= 1) {
        int v = (tid >= d) ? ps[tid - d] : 0;
        __syncthreads();
        ps[tid] += v;
        __syncthreads();
    }
    int excl = ps[tid] - s;
    #pragma unroll
    for (int i = 0; i < 32; i++) {
        int o = excl + loc[i];
        off[base + i] = o;
        cursor[base + i] = o;
        int dg = ideg[base + i];
        rs[base + i] = dg > 0 ? rsqrtf((float)dg) : 0.f;
    }
    if (tid == 255) off[8192] = excl + s;
}

__global__ void fill_csr(const int* __restrict__ adj, int* __restrict__ cursor,
                         int* __restrict__ csr) {
    int e = blockIdx.x * 256 + threadIdx.x;
    if (e < EE) {
        int col = adj[EE + e];
        int pos = atomicAdd(&cursor[col], 1);
        csr[pos] = adj[e];
    }
}

// block = destination node; coalesced 1KB row gathers, f32 reg accumulate, bf16 out
__global__ __launch_bounds__(256) void gcn_gather(const float* __restrict__ x,
        const int* __restrict__ csr, const int* __restrict__ off,
        const float* __restrict__ rs, bf16* __restrict__ hib) {
    const int col = blockIdx.x;
    const int t = threadIdx.x;
    const int o = off[col];
    const int cnt = off[col + 1] - o;
    const float rsc = rs[col];
    float acc = 0.f;
    int e = 0;
    for (; e + 4 <= cnt; e += 4) {
        int r0 = csr[o + e], r1 = csr[o + e + 1], r2 = csr[o + e + 2], r3 = csr[o + e + 3];
        float v0 = rsc * rs[r0], v1 = rsc * rs[r1], v2 = rsc * rs[r2], v3 = rsc * rs[r3];
        acc += x[(size_t)r0 * CC + t] * v0 + x[(size_t)r1 * CC + t] * v1
             + x[(size_t)r2 * CC + t] * v2 + x[(size_t)r3 * CC + t] * v3;
    }
    for (; e < cnt; e++) {
        int r0 = csr[o + e];
        acc += x[(size_t)r0 * CC + t] * (rsc * rs[r0]);
    }
    hib[(size_t)col * CC + t] = f2bf(acc);
}

// ---------------------------------------------------------------- BT GEMM
// C[M,N] = A[M,K] * W[N,K]^T (+bias).  A,W bf16 row-major.
__global__ __launch_bounds__(256) void gemm_bt(
        const bf16* __restrict__ A, const bf16* __restrict__ W,
        const float* __restrict__ bias,
        float* __restrict__ outF, bf16* __restrict__ outB,
        int M, int N, int K) {
    const int tid  = threadIdx.x;
    const int wave = tid >> 6;
    const int lane = tid & 63;
    const int quad = lane >> 4;
    const int l15  = lane & 15;
    const int m0 = blockIdx.x * 128;
    const int n0 = blockIdx.y * 64;

    __shared__ bf16 Alds[128][72];
    __shared__ bf16 Wlds[64][72];

    f32x4 acc[2][4];
    #pragma unroll
    for (int mt = 0; mt < 2; mt++)
        #pragma unroll
        for (int nt = 0; nt < 4; nt++)
            acc[mt][nt] = (f32x4){0.f, 0.f, 0.f, 0.f};

    for (int k0 = 0; k0 < K; k0 += 64) {
        #pragma unroll
        for (int i = 0; i < 4; i++) {
            int u = tid + i * 256;
            int r = u >> 3;
            int cp = u & 7;
            *reinterpret_cast<bf16x8*>(&Alds[r][cp * 8]) =
                *reinterpret_cast<const bf16x8*>(A + (size_t)(m0 + r) * K + k0 + cp * 8);
        }
        #pragma unroll
        for (int i = 0; i < 2; i++) {
            int u = tid + i * 256;
            int r = u >> 3;
            int cp = u & 7;
            *reinterpret_cast<bf16x8*>(&Wlds[r][cp * 8]) =
                *reinterpret_cast<const bf16x8*>(W + (size_t)(n0 + r) * K + k0 + cp * 8);
        }
        __syncthreads();
        #pragma unroll
        for (int c = 0; c < 2; c++) {
            bf16x8 af[2], wf[4];
            #pragma unroll
            for (int mt = 0; mt < 2; mt++)
                af[mt] = *reinterpret_cast<const bf16x8*>(&Alds[wave * 32 + mt * 16 + l15][c * 32 + quad * 8]);
            #pragma unroll
            for (int nt = 0; nt < 4; nt++)
                wf[nt] = *reinterpret_cast<const bf16x8*>(&Wlds[nt * 16 + l15][c * 32 + quad * 8]);
            #pragma unroll
            for (int mt = 0; mt < 2; mt++)
                #pragma unroll
                for (int nt = 0; nt < 4; nt++)
                    acc[mt][nt] = __builtin_amdgcn_mfma_f32_16x16x32_bf16(af[mt], wf[nt], acc[mt][nt], 0, 0, 0);
        }
        __syncthreads();
    }
    #pragma unroll
    for (int mt = 0; mt < 2; mt++)
        #pragma unroll
        for (int nt = 0; nt < 4; nt++)
            #pragma unroll
            for (int r = 0; r < 4; r++) {
                int m = m0 + wave * 32 + mt * 16 + quad * 4 + r;
                int n = n0 + nt * 16 + l15;
                float v = acc[mt][nt][r];
                if (bias) v += bias[n];
                if (outF) outF[(size_t)m * N + n] = v;
                else      outB[(size_t)m * N + n] = f2bf(v);
            }
}

// ---------------------------------------------------------------- flash attention v3
// S^T trick (softmax per-lane, q=lane&15) + reg-direct PV + BK=128:
// two 64-key sub-tiles share one softmax round -> half the shuffles/rescales/barriers.
// grid 512: h = bx&3 (one head per XCD -> K/V L2 locality), qb = bx>>2 (64 q rows).
__global__ __launch_bounds__(256, 2) void flash_attn3(const bf16* __restrict__ qkv,
                                                      const bf16* __restrict__ vT,
                                                      bf16* __restrict__ attnO) {
    const int tid  = threadIdx.x;
    const int wave = tid >> 6;
    const int lane = tid & 63;
    const int quad = lane >> 4;
    const int l15  = lane & 15;
    const int bx = blockIdx.x;
    const int h  = bx & 3;
    const int qb = bx >> 2;
    const int qbase = qb * 64;

    __shared__ bf16 Klds[2][2][64][64];   // [dbuf][sub][key][d], granule-swizzled
    __shared__ bf16 Vlds[2][2][64][64];   // [dbuf][sub][d][key], granule-swizzled

    // Q fragment (B operand: n=q=l15, k=d=quad*8+j), prescaled by 1/sqrt(DH)=1/8
    const int qrow = qbase + wave * 16 + l15;
    bf16x8 qf[2];
    #pragma unroll
    for (int c = 0; c < 2; c++) {
        bf16x8 raw = *reinterpret_cast<const bf16x8*>(qkv + (size_t)qrow * 768 + h * 64 + c * 32 + quad * 8);
        #pragma unroll
        for (int j = 0; j < 8; j++) qf[c][j] = f2bf((float)raw[j] * 0.125f);
    }

    // QK A-operand rows: permuted keys so exp'd S^T regs are the exact PV A-operand.
    int koff[4][2], voff[4][2];
    #pragma unroll
    for (int t = 0; t < 4; t++) {
        int kr = 32 * (t >> 1) + 8 * (l15 >> 2) + 4 * (t & 1) + (l15 & 3);
        int fk = ((kr >> 3) & 3) + ((kr & 2) << 1);
        #pragma unroll
        for (int c = 0; c < 2; c++)
            koff[t][c] = kr * 64 + ((((c * 4 + quad) ^ fk)) << 3);
        int dd = t * 16 + l15;
        #pragma unroll
        for (int c = 0; c < 2; c++)
            voff[t][c] = dd * 64 + ((((c * 4 + quad) ^ (dd & 7))) << 3);
    }

    int srcK[2], srcV[2], dstK[2], dstV[2];
    #pragma unroll
    for (int i = 0; i < 2; i++) {
        int u = tid + i * 256;
        int r = u >> 3, g = u & 7;
        int fk = ((r >> 3) & 3) + ((r & 2) << 1);
        dstK[i] = r * 64 + ((g ^ fk) << 3);
        dstV[i] = r * 64 + ((g ^ (r & 7)) << 3);
        srcK[i] = r * 768 + 256 + h * 64 + g * 8;   // + tile*64*768
        srcV[i] = (h * 64 + r) * 8192 + g * 8;      // + tile*64
    }

    f32x4 oacc[4];
    #pragma unroll
    for (int nt = 0; nt < 4; nt++) oacc[nt] = (f32x4){0.f, 0.f, 0.f, 0.f};
    float m_run = -INFINITY, l_run = 0.f;

    // prologue: tiles 0,1 -> dbuf 0
    #pragma unroll
    for (int s = 0; s < 2; s++)
        #pragma unroll
        for (int i = 0; i < 2; i++) {
            *reinterpret_cast<bf16x8*>(&Klds[0][s][0][0] + dstK[i]) =
                *reinterpret_cast<const bf16x8*>(qkv + (size_t)s * 64 * 768 + srcK[i]);
            *reinterpret_cast<bf16x8*>(&Vlds[0][s][0][0] + dstV[i]) =
                *reinterpret_cast<const bf16x8*>(vT + s * 64 + srcV[i]);
        }
    __syncthreads();

    for (int it = 0; it < 64; it++) {
        const int p = it & 1;
        bf16x8 stK[2][2], stV[2][2];
        if (it < 63) {
            #pragma unroll
            for (int s = 0; s < 2; s++)
                #pragma unroll
                for (int i = 0; i < 2; i++) {
                    stK[s][i] = *reinterpret_cast<const bf16x8*>(
                        qkv + (size_t)(2 * it + 2 + s) * 64 * 768 + srcK[i]);
                    stV[s][i] = *reinterpret_cast<const bf16x8*>(
                        vT + (2 * it + 2 + s) * 64 + srcV[i]);
                }
        }
        const bf16* Kb0 = &Klds[p][0][0][0];
        const bf16* Kb1 = &Klds[p][1][0][0];
        const bf16* Vb0 = &Vlds[p][0][0][0];
        const bf16* Vb1 = &Vlds[p][1][0][0];

        // S^T = K . Q^T over 128 keys (2 sub-tiles)
        f32x4 sacc[2][4];
        #pragma unroll
        for (int s = 0; s < 2; s++)
            #pragma unroll
            for (int t = 0; t < 4; t++) sacc[s][t] = (f32x4){0.f, 0.f, 0.f, 0.f};
        #pragma unroll
        for (int c = 0; c < 2; c++)
            #pragma unroll
            for (int t = 0; t < 4; t++) {
                bf16x8 a0 = *reinterpret_cast<const bf16x8*>(Kb0 + koff[t][c]);
                bf16x8 a1 = *reinterpret_cast<const bf16x8*>(Kb1 + koff[t][c]);
                sacc[0][t] = __builtin_amdgcn_mfma_f32_16x16x32_bf16(a0, qf[c], sacc[0][t], 0, 0, 0);
                sacc[1][t] = __builtin_amdgcn_mfma_f32_16x16x32_bf16(a1, qf[c], sacc[1][t], 0, 0, 0);
            }

        // one online-softmax round for 128 keys (q = l15 per lane)
        float tmax = -INFINITY;
        #pragma unroll
        for (int s = 0; s < 2; s++)
            #pragma unroll
            for (int t = 0; t < 4; t++)
                #pragma unroll
                for (int r = 0; r < 4; r++) tmax = fmaxf(tmax, sacc[s][t][r]);
        tmax = fmaxf(tmax, __shfl_xor(tmax, 16));
        tmax = fmaxf(tmax, __shfl_xor(tmax, 32));
        float mnew = fmaxf(m_run, tmax);
        float al = __expf(m_run - mnew);
        float rsum = 0.f;
        bf16x8 pf[2][2];
        #pragma unroll
        for (int s = 0; s < 2; s++)
            #pragma unroll
            for (int t = 0; t < 4; t++)
                #pragma unroll
                for (int r = 0; r < 4; r++) {
                    float pv = __expf(sacc[s][t][r] - mnew);
                    rsum += pv;
                    pf[s][t >> 1][(t & 1) * 4 + r] = f2bf(pv);
                }
        rsum += __shfl_xor(rsum, 16);
        rsum += __shfl_xor(rsum, 32);
        l_run = l_run * al + rsum;
        m_run = mnew;

        #pragma unroll
        for (int r = 0; r < 4; r++) {
            float ar = __shfl(al, quad * 4 + r);
            #pragma unroll
            for (int nt = 0; nt < 4; nt++) oacc[nt][r] *= ar;
        }

        // O += P.V  (P direct from regs)
        #pragma unroll
        for (int c = 0; c < 2; c++)
            #pragma unroll
            for (int nt = 0; nt < 4; nt++) {
                bf16x8 b0 = *reinterpret_cast<const bf16x8*>(Vb0 + voff[nt][c]);
                bf16x8 b1 = *reinterpret_cast<const bf16x8*>(Vb1 + voff[nt][c]);
                oacc[nt] = __builtin_amdgcn_mfma_f32_16x16x32_bf16(pf[0][c], b0, oacc[nt], 0, 0, 0);
                oacc[nt] = __builtin_amdgcn_mfma_f32_16x16x32_bf16(pf[1][c], b1, oacc[nt], 0, 0, 0);
            }

        if (it < 63) {
            #pragma unroll
            for (int s = 0; s < 2; s++)
                #pragma unroll
                for (int i = 0; i < 2; i++) {
                    *reinterpret_cast<bf16x8*>(&Klds[p ^ 1][s][0][0] + dstK[i]) = stK[s][i];
                    *reinterpret_cast<bf16x8*>(&Vlds[p ^ 1][s][0][0] + dstV[i]) = stV[s][i];
                }
        }
        __syncthreads();
    }

    float linv = 1.f / l_run;
    #pragma unroll
    for (int r = 0; r < 4; r++) {
        float lr = __shfl(linv, quad * 4 + r);
        int q = qbase + wave * 16 + quad * 4 + r;
        #pragma unroll
        for (int nt = 0; nt < 4; nt++)
            attnO[(size_t)q * CC + h * 64 + nt * 16 + l15] = f2bf(oacc[nt][r] * lr);
    }
}

// ---------------------------------------------------------------- LN + combine
__global__ __launch_bounds__(256) void ln_combine(
        const float* __restrict__ x, const float* __restrict__ aproj,
        const float* __restrict__ local,
        const float* __restrict__ g, const float* __restrict__ b,
        const float* __restrict__ alpha_p, bf16* __restrict__ comb) {
    int row = blockIdx.x;
    int t = threadIdx.x;
    __shared__ float red[256];
    float v = x[(size_t)row * CC + t] + aproj[(size_t)row * CC + t];
    red[t] = v;
    __syncthreads();
    for (int s = 128; s > 0; s >>= 1) { if (t < s) red[t] += red[t + s]; __syncthreads(); }
    float mu = red[0] * (1.f / CC);
    __syncthreads();
    float d = v - mu;
    red[t] = d * d;
    __syncthreads();
    for (int s = 128; s > 0; s >>= 1) { if (t < s) red[t] += red[t + s]; __syncthreads(); }
    float var = red[0] * (1.f / CC);
    float rstd = rsqrtf(var + 1e-5f);
    float ln = d * rstd * g[t] + b[t];
    float w = 1.f / (1.f + __expf(-alpha_p[0]));
    comb[(size_t)row * CC + t] = f2bf(w * local[(size_t)row * CC + t] + (1.f - w) * ln);
}

// ---------------------------------------------------------------- launch
extern "C" void kernel_launch(void* const* d_in, const int* in_sizes, int n_in,
                              void* d_out, int out_size, void* d_ws, size_t ws_size,
                              hipStream_t stream) {
    (void)in_sizes; (void)n_in; (void)out_size; (void)ws_size;
    const float* x    = (const float*)d_in[0];
    const int*   adj  = (const int*)d_in[1];
    const float* wloc = (const float*)d_in[2];
    const float* ipw  = (const float*)d_in[3];
    const float* ipb  = (const float*)d_in[4];
    const float* opw  = (const float*)d_in[5];
    const float* opb  = (const float*)d_in[6];
    const float* lng  = (const float*)d_in[7];
    const float* lnb  = (const float*)d_in[8];
    const float* alp  = (const float*)d_in[9];
    const float* fcw  = (const float*)d_in[10];
    const float* fcb  = (const float*)d_in[11];
    float* out = (float*)d_out;

    char* p = (char*)d_ws;
    int*   ideg   = (int*)p;    p += (size_t)NN * 4;
    int*   off    = (int*)p;    p += (size_t)(NN + 1) * 4;
    int*   cursor = (int*)p;    p += (size_t)NN * 4;
    float* rs     = (float*)p;  p += (size_t)NN * 4;
    int*   csr    = (int*)p;    p += (size_t)EE * 4;
    bf16* xb    = (bf16*)p;   p += (size_t)NN * CC * 2;
    bf16* hib   = (bf16*)p;   p += (size_t)NN * CC * 2;
    bf16* ipwb  = (bf16*)p;   p += (size_t)768 * 256 * 2;
    bf16* wlTb  = (bf16*)p;   p += (size_t)256 * 256 * 2;
    bf16* opwb  = (bf16*)p;   p += (size_t)256 * 256 * 2;
    bf16* fcwb  = (bf16*)p;   p += (size_t)256 * 256 * 2;
    bf16* qkvb  = (bf16*)p;   p += (size_t)NN * 768 * 2;
    bf16* vT    = (bf16*)p;   p += (size_t)NN * CC * 2;
    bf16* aOb   = (bf16*)p;   p += (size_t)NN * CC * 2;
    float* aprj = (float*)p;  p += (size_t)NN * CC * 4;
    float* locl = (float*)p;  p += (size_t)NN * CC * 4;
    bf16* comb  = (bf16*)p;   p += (size_t)NN * CC * 2;

    hipMemsetAsync(ideg, 0, (size_t)NN * 4, stream);

    cvt_f32_bf16<<<2048, 256, 0, stream>>>(x, xb, NN * CC);
    cvt_f32_bf16<<<768, 256, 0, stream>>>(ipw, ipwb, 768 * 256);
    cvt_f32_bf16<<<256, 256, 0, stream>>>(opw, opwb, 256 * 256);
    cvt_f32_bf16<<<256, 256, 0, stream>>>(fcw, fcwb, 256 * 256);
    transpose_cvt<<<256, 256, 0, stream>>>(wloc, wlTb);

    // GCN: degree -> CSR -> gather (writes hib bf16 directly)
    degree_i<<<EE / 256, 256, 0, stream>>>(adj, ideg);
    scan_offsets<<<1, 256, 0, stream>>>(ideg, off, cursor, rs);
    fill_csr<<<EE / 256, 256, 0, stream>>>(adj, cursor, csr);
    gcn_gather<<<NN, 256, 0, stream>>>(x, csr, off, rs, hib);

    gemm_bt<<<dim3(NN / 128, 768 / 64), 256, 0, stream>>>(xb, ipwb, ipb, nullptr, qkvb, NN, 768, 256);
    build_vT<<<dim3(NN / 64, 4), 256, 0, stream>>>(qkvb, vT);
    flash_attn3<<<512, 256, 0, stream>>>(qkvb, vT, aOb);
    gemm_bt<<<dim3(NN / 128, 256 / 64), 256, 0, stream>>>(aOb, opwb, opb, aprj, nullptr, NN, 256, 256);
    gemm_bt<<<dim3(NN / 128, 256 / 64), 256, 0, stream>>>(hib, wlTb, nullptr, locl, nullptr, NN, 256, 256);
    ln_combine<<<NN, 256, 0, stream>>>(x, aprj, locl, lng, lnb, alp, comb);
    gemm_bt<<<dim3(NN / 128, 256 / 64), 256, 0, stream>>>(comb, fcwb, fcb, out, nullptr, NN, 256, 256);
}